// Round 14
// baseline (241.086 us; speedup 1.0000x reference)
//
#include <hip/hip_runtime.h>
#include <hip/hip_bf16.h>

typedef unsigned short u16;
typedef unsigned int u32;
typedef __attribute__((ext_vector_type(8))) short bf16x8;
typedef __attribute__((ext_vector_type(4))) float f32x4;

#define LOG2E 1.44269504088896340736f
#define QSCALE (0.125f * LOG2E)
#define DEFER_THR 8.0f

// ---------- helpers ----------

__device__ inline u16 f2bf(float f) {            // RNE
  union { float f; u32 u; } v; v.f = f;
  u32 r = v.u + 0x7fffu + ((v.u >> 16) & 1u);
  return (u16)(r >> 16);
}

__device__ inline void gload_lds16(const void* g, void* l) {
  __builtin_amdgcn_global_load_lds(
      (const __attribute__((address_space(1))) u32*)g,
      (__attribute__((address_space(3))) u32*)l, 16, 0, 0);
}

// DPP move within 16-lane rows (row_ror:N = 0x120+N)
template<int CTRL>
__device__ inline float dppmov(float x) {
  int i = __builtin_bit_cast(int, x);
  int r = __builtin_amdgcn_update_dpp(i, i, CTRL, 0xf, 0xf, false);
  return __builtin_bit_cast(float, r);
}
__device__ inline float rowmax16(float v) {
  v = fmaxf(v, dppmov<0x128>(v));
  v = fmaxf(v, dppmov<0x124>(v));
  v = fmaxf(v, dppmov<0x122>(v));
  v = fmaxf(v, dppmov<0x121>(v));
  return v;
}
__device__ inline float rowsum16(float v) {
  v += dppmov<0x128>(v);
  v += dppmov<0x124>(v);
  v += dppmov<0x122>(v);
  v += dppmov<0x121>(v);
  return v;
}

// ---------- fp32 -> bf16: all 7 tensors in ONE dispatch ----------

__global__ void cvt_all(const float4* __restrict__ q, const float4* __restrict__ k,
                        const float4* __restrict__ v,
                        const float4* __restrict__ Wq, const float4* __restrict__ Wk,
                        const float4* __restrict__ Wv, const float4* __restrict__ Wo,
                        ushort4* __restrict__ dq, ushort4* __restrict__ dk,
                        ushort4* __restrict__ dv,
                        ushort4* __restrict__ dWq, ushort4* __restrict__ dWk,
                        ushort4* __restrict__ dWv, ushort4* __restrict__ dWo,
                        int n4A, int n4W) {
  const float4* s; ushort4* d; int n4;
  switch (blockIdx.y) {
    case 0: s = q;  d = dq;  n4 = n4A; break;
    case 1: s = k;  d = dk;  n4 = n4A; break;
    case 2: s = v;  d = dv;  n4 = n4A; break;
    case 3: s = Wq; d = dWq; n4 = n4W; break;
    case 4: s = Wk; d = dWk; n4 = n4W; break;
    case 5: s = Wv; d = dWv; n4 = n4W; break;
    default: s = Wo; d = dWo; n4 = n4W; break;
  }
  int stride = gridDim.x * blockDim.x;
  for (int i = blockIdx.x * blockDim.x + threadIdx.x; i < n4; i += stride) {
    float4 x = s[i];
    ushort4 o;
    o.x = f2bf(x.x); o.y = f2bf(x.y); o.z = f2bf(x.z); o.w = f2bf(x.w);
    d[i] = o;
  }
}

// ---------- per-(b, kv-tile) padding-mask OR flags ----------

__global__ void mask_flags(const unsigned char* __restrict__ mask,
                           unsigned char* __restrict__ flags) {
  int t = threadIdx.x;   // 0..127
  if (t >= 128) return;
  const uint4* p = (const uint4*)(mask + (size_t)t * 64);
  uint4 a = p[0], b = p[1], c = p[2], d = p[3];
  u32 v = a.x | a.y | a.z | a.w | b.x | b.y | b.z | b.w |
          c.x | c.y | c.z | c.w | d.x | d.y | d.z | d.w;
  flags[t] = v ? 1 : 0;
}

// ---------- 8-phase QKV projection, BALANCED geometry ----------
// BM=256, BN=128, BK=64. Grid (8,32,3)=768 blocks = EXACTLY 3 rounds on 256 CUs
// (fixes r10's 1.5-round imbalance). 8 waves: wm=wave>>1 (64 rows), wn=wave&1
// (64 cols); per-wave 4x4 frags. LDS 96KB: sA[2buf][2half][128x64],
// sB[2buf][2half][64x64], XOR-swizzled (T2). Per K-tile: 4 phases, each
// {ds_read subtile | stage one unit | gate | 8 MFMA w/ setprio}.
// Stage units: Bh1(t+1)@s1, Ah1(t+1)@s2, Bh0(t+2)@s3, Ah0(t+2)@s4 -- each
// slot's previous data was last read >=2 barriers before its overwrite lands.
// Gates: barrier-only at s1-s3; vmcnt(3) at s4 (keeps t+2's 3 loads in flight,
// retires all of t+1); vmcnt(0) at the epilogue boundary (fixes r10 race).

#define BAR8() do { \
    __builtin_amdgcn_s_barrier(); \
    __builtin_amdgcn_sched_barrier(0); \
  } while (0)

#define READ_A8(buf, qm)                                                       \
  do {                                                                         \
    const char* ab_ = (const char*)&sA[buf][wm >> 1][0];                       \
    _Pragma("unroll")                                                          \
    for (int fi = 0; fi < 2; ++fi) {                                           \
      _Pragma("unroll")                                                        \
      for (int kk = 0; kk < 2; ++kk) {                                         \
        int row_ = (wm & 1) * 64 + (qm) * 32 + fi * 16 + r;                    \
        int j_ = kk * 4 + g;                                                   \
        af[fi][kk] = *(const bf16x8*)(ab_ + row_ * 128 +                       \
                                      ((j_ ^ (row_ & 7)) << 4));               \
      }                                                                        \
    }                                                                          \
  } while (0)

#define READ_B8(buf, qn, BF)                                                   \
  do {                                                                         \
    const char* bb_ = (const char*)&sB[buf][wn][0];                            \
    _Pragma("unroll")                                                          \
    for (int fj = 0; fj < 2; ++fj) {                                           \
      _Pragma("unroll")                                                        \
      for (int kk = 0; kk < 2; ++kk) {                                         \
        int row_ = (qn) * 32 + fj * 16 + r;                                    \
        int j_ = kk * 4 + g;                                                   \
        BF[fj][kk] = *(const bf16x8*)(bb_ + row_ * 128 +                       \
                                      ((j_ ^ (row_ & 7)) << 4));               \
      }                                                                        \
    }                                                                          \
  } while (0)

#define MFMA8B(qm, qn, BF)                                                     \
  do {                                                                         \
    __builtin_amdgcn_s_setprio(1);                                             \
    _Pragma("unroll")                                                          \
    for (int kk = 0; kk < 2; ++kk) {                                           \
      _Pragma("unroll")                                                        \
      for (int fi = 0; fi < 2; ++fi) {                                         \
        _Pragma("unroll")                                                      \
        for (int fj = 0; fj < 2; ++fj) {                                       \
          acc[(qm) * 2 + fi][(qn) * 2 + fj] =                                  \
              __builtin_amdgcn_mfma_f32_16x16x32_bf16(                         \
                  af[fi][kk], BF[fj][kk], acc[(qm) * 2 + fi][(qn) * 2 + fj],   \
                  0, 0, 0);                                                    \
        }                                                                      \
      }                                                                        \
    }                                                                          \
    __builtin_amdgcn_s_setprio(0);                                             \
  } while (0)

__global__ __launch_bounds__(512) void gemm_qkv8b(
    const u16* __restrict__ Aq, const u16* __restrict__ Ak, const u16* __restrict__ Av,
    const u16* __restrict__ Wqb, const u16* __restrict__ Wkb, const u16* __restrict__ Wvb,
    const float* __restrict__ bqp, const float* __restrict__ bkp, const float* __restrict__ bvp,
    u16* __restrict__ Qh, u16* __restrict__ Kh, u16* __restrict__ Vt,
    int M, int N, int K) {
  __shared__ u16 sA[2][2][128 * 64];   // 64 KB
  __shared__ u16 sB[2][2][64 * 64];    // 32 KB

  // XCD-chunked bijective swizzle (nwg = 8*32*3 = 768, %8==0)
  const int hw = blockIdx.z * 256 + blockIdx.y * 8 + blockIdx.x;
  const int lg = (hw & 7) * 96 + (hw >> 3);
  const int z = lg >> 8;           // /256
  const int rem = lg & 255;
  const int m0 = (rem >> 3) * 256;
  const int n0 = (rem & 7) * 128;

  const u16* A  = (z == 0) ? Aq : (z == 1) ? Ak : Av;
  const u16* Bt = (z == 0) ? Wqb : (z == 1) ? Wkb : Wvb;
  const float* bias = (z == 0) ? bqp : (z == 1) ? bkp : bvp;

  const int tid = threadIdx.x;
  const int lane = tid & 63;
  const int wave = tid >> 6;       // 0..7
  const int g = lane >> 4;
  const int r = lane & 15;
  const int wm = wave >> 1;        // 0..3  (64 rows each)
  const int wn = wave & 1;         // 0..1  (64 cols each)

  f32x4 acc[4][4] = {};
  bf16x8 af[2][2], bf0[2][2], bf1[2][2];

  auto stageA = [&](int buf, int half, int kt) {   // 2 loads/thread
    const int k0 = kt * 64;
#pragma unroll
    for (int i = 0; i < 2; ++i) {
      int c = tid + i * 512;
      int row = c >> 3, cc = c & 7;
      gload_lds16(A + (size_t)(m0 + half * 128 + row) * K + k0 + ((cc ^ (row & 7)) * 8),
                  &sA[buf][half][0] + c * 8);
    }
  };
  auto stageB = [&](int buf, int half, int kt) {   // 1 load/thread
    const int k0 = kt * 64;
    int c = tid;
    int row = c >> 3, cc = c & 7;
    gload_lds16(Bt + (size_t)(n0 + half * 64 + row) * K + k0 + ((cc ^ (row & 7)) * 8),
                &sB[buf][half][0] + c * 8);
  };

  const int NT = K / 64;   // 16

  // prologue: tile0 complete + tile1 {Bh0, Ah0}; retire tile0 (keep 3 in flight)
  stageB(0, 0, 0); stageB(0, 1, 0); stageA(0, 0, 0); stageA(0, 1, 0);
  stageB(1, 0, 1); stageA(1, 0, 1);
  asm volatile("s_waitcnt vmcnt(3)" ::: "memory");
  BAR8();

  for (int t = 0; t < NT; ++t) {
    const int buf = t & 1;
    // ---- s1: quadrant (0,0); stage Bh1(t+1) ----
    READ_A8(buf, 0);
    READ_B8(buf, 0, bf0);
    if (t + 1 < NT) stageB(buf ^ 1, 1, t + 1);
    BAR8();
    MFMA8B(0, 0, bf0);
    // ---- s2: quadrant (0,1); stage Ah1(t+1) ----
    READ_B8(buf, 1, bf1);
    if (t + 1 < NT) stageA(buf ^ 1, 1, t + 1);
    BAR8();
    MFMA8B(0, 1, bf1);
    // ---- s3: quadrant (1,0); stage Bh0(t+2) ----
    READ_A8(buf, 1);
    if (t + 2 < NT) stageB(buf, 0, t + 2);
    BAR8();
    MFMA8B(1, 0, bf0);
    // ---- s4: quadrant (1,1); stage Ah0(t+2); tile-boundary gate ----
    if (t + 2 < NT) {
      stageA(buf, 0, t + 2);
      asm volatile("s_waitcnt vmcnt(3)" ::: "memory");   // t+1 landed; t+2 in flight
    } else if (t + 1 < NT) {
      asm volatile("s_waitcnt vmcnt(0)" ::: "memory");   // epilogue: drain exactly
    }
    BAR8();
    MFMA8B(1, 1, bf1);
  }

  // epilogue: bias + head-layout stores
#pragma unroll
  for (int fi = 0; fi < 4; ++fi) {
    int rowb = m0 + wm * 64 + fi * 16 + g * 4;
#pragma unroll
    for (int fj = 0; fj < 4; ++fj) {
      int col = n0 + wn * 64 + fj * 16 + r;
      float bv = bias[col];
#pragma unroll
      for (int q = 0; q < 4; ++q) {
        int row = rowb + q;
        float v = acc[fi][fj][q] + bv;
        int b = row >> 10, t = row & 1023, h = col >> 6, d = col & 63;
        if (z == 0) {
          Qh[((((size_t)b * 16 + h) << 10) + t) * 64 + d] = f2bf(v * QSCALE);
        } else if (z == 1) {
          Kh[((((size_t)b * 16 + h) << 10) + t) * 64 + d] = f2bf(v);
        } else {
          Vt[(((size_t)b * 16 + h) * 64 + d) * 1024 + t] = f2bf(v);
        }
      }
    }
  }
}

// ---------- O-projection GEMM (r9: 2-phase + XCD swizzle, frozen) ----------

__global__ __launch_bounds__(256) void gemm_o(
    const u16* __restrict__ A, const u16* __restrict__ Bt,
    const float* __restrict__ bias, float* __restrict__ Cout,
    int M, int N, int K) {
  constexpr int BK = 32;
  __shared__ u16 sA[2][128 * BK];
  __shared__ u16 sB[2][128 * BK];

  const int hw = blockIdx.y * 8 + blockIdx.x;   // grid (8,64) = 512
  const int lg = (hw & 7) * 64 + (hw >> 3);
  const int m0 = (lg >> 3) * 128;
  const int n0 = (lg & 7) * 128;

  const int tid = threadIdx.x;
  const int lane = tid & 63;
  const int wave = tid >> 6;
  const int g = lane >> 4;
  const int r = lane & 15;
  const int wr = wave >> 1, wc = wave & 1;

  f32x4 acc[4][4] = {};

  auto stage = [&](int buf, int kt) {
    const int k0 = kt * BK;
#pragma unroll
    for (int i = 0; i < 2; ++i) {
      int c = tid + i * 256;
      int row = c >> 2, cc = c & 3;
      gload_lds16(A + (size_t)(m0 + row) * K + k0 + cc * 8, &sA[buf][0] + c * 8);
    }
#pragma unroll
    for (int i = 0; i < 2; ++i) {
      int c = tid + i * 256;
      int row = c >> 2, cc = c & 3;
      gload_lds16(Bt + (size_t)(n0 + row) * K + k0 + cc * 8, &sB[buf][0] + c * 8);
    }
  };

  stage(0, 0);
  const int NT = K / BK;
  for (int kt = 0; kt < NT; ++kt) {
    __syncthreads();
    if (kt + 1 < NT) stage((kt + 1) & 1, kt + 1);
    const u16* a_base = &sA[kt & 1][0];
    const u16* b_base = &sB[kt & 1][0];
    bf16x8 avf[4], bvf[4];
#pragma unroll
    for (int i = 0; i < 4; ++i) {
      avf[i] = *(const bf16x8*)(a_base + (wr * 64 + i * 16 + r) * BK + g * 8);
      bvf[i] = *(const bf16x8*)(b_base + (wc * 64 + i * 16 + r) * BK + g * 8);
    }
#pragma unroll
    for (int i = 0; i < 4; ++i)
#pragma unroll
      for (int j = 0; j < 4; ++j)
        acc[i][j] = __builtin_amdgcn_mfma_f32_16x16x32_bf16(avf[i], bvf[j], acc[i][j], 0, 0, 0);
  }

#pragma unroll
  for (int i = 0; i < 4; ++i) {
    int rowb = m0 + wr * 64 + i * 16 + g * 4;
#pragma unroll
    for (int j = 0; j < 4; ++j) {
      int col = n0 + wc * 64 + j * 16 + r;
      float bv = bias[col];
#pragma unroll
      for (int q = 0; q < 4; ++q) {
        int row = rowb + q;
        Cout[(size_t)row * N + col] = acc[i][j][q] + bv;
      }
    }
  }
}

// ---------- flash attention (r9 best: 4 waves, grid 128x8, defer-max, setprio) ----------

__global__ __launch_bounds__(256) void attn_fwd(
    const u16* __restrict__ Qh, const u16* __restrict__ Kh,
    const u16* __restrict__ Vt, const unsigned char* __restrict__ mask,
    const unsigned char* __restrict__ padflags,
    u16* __restrict__ O) {
  constexpr int S = 1024, DH = 64;
  __shared__ u16 sK[2][64 * 64];
  __shared__ u16 sV[2][64 * 64];
  __shared__ u16 sP[4][16 * 64];

  const int tid = threadIdx.x, lane = tid & 63, wave = tid >> 6;
  const int g = lane >> 4, r = lane & 15;
  const int bh = blockIdx.x;
  const int qt = (int)gridDim.y - 1 - (int)blockIdx.y;   // LPT: heavy first
  const int b = bh >> 4, h = bh & 15;
  const int qw = qt * 128 + wave * 32;

  bf16x8 qf[2][2];
#pragma unroll
  for (int u = 0; u < 2; ++u) {
    const u16* Qb = Qh + ((size_t)bh * S + qw + u * 16 + r) * DH;
    qf[u][0] = *(const bf16x8*)(Qb + g * 8);
    qf[u][1] = *(const bf16x8*)(Qb + 32 + g * 8);
  }

  f32x4 acc[2][4] = {};
  float mrun[2][4], lrun[2][4];
#pragma unroll
  for (int u = 0; u < 2; ++u)
#pragma unroll
    for (int i = 0; i < 4; ++i) { mrun[u][i] = -INFINITY; lrun[u][i] = 0.f; }

  auto stage = [&](int buf, int kvt) {
    const int s0k = kvt * 64;
#pragma unroll
    for (int i = 0; i < 2; ++i) {
      int c = tid + i * 256;
      int row = c >> 3;
      int cc = (c & 7) ^ (row & 7);
      gload_lds16(Kh + ((size_t)bh * S + s0k + row) * DH + cc * 8, &sK[buf][0] + c * 8);
      gload_lds16(Vt + ((size_t)bh * DH + row) * S + s0k + cc * 8, &sV[buf][0] + c * 8);
    }
  };

  const int NT = 2 * (qt + 1);
  stage(0, 0);
  for (int kvt = 0; kvt < NT; ++kvt) {
    __syncthreads();
    if (kvt + 1 < NT) stage((kvt + 1) & 1, kvt + 1);
    const int cur = kvt & 1;
    const int s0 = kvt * 64;
    const bool pad = padflags[b * 16 + (s0 >> 6)] != 0;
    const u16* Kb = &sK[cur][0];
    const u16* Vb = &sV[cur][0];
    u16* Pw = &sP[wave][0];

#pragma unroll
    for (int u = 0; u < 2; ++u) {
      const int qg = qw + u * 16;
      if (s0 > qg + 15) continue;
      const bool diag = (s0 + 63 > qg);

      f32x4 sc[4] = {};
      __builtin_amdgcn_s_setprio(1);
#pragma unroll
      for (int ss = 0; ss < 4; ++ss) {
#pragma unroll
        for (int kc = 0; kc < 2; ++kc) {
          int krow = ss * 16 + r;
          int byteoff = krow * 128 + kc * 64 + g * 16;
          bf16x8 kf = *(const bf16x8*)((const char*)Kb + (byteoff ^ ((krow & 7) << 4)));
          sc[ss] = __builtin_amdgcn_mfma_f32_16x16x32_bf16(qf[u][kc], kf, sc[ss], 0, 0, 0);
        }
      }
      __builtin_amdgcn_s_setprio(0);

      float sv[4][4];
      float pmax[4] = {-INFINITY, -INFINITY, -INFINITY, -INFINITY};
#pragma unroll
      for (int ss = 0; ss < 4; ++ss) {
        float padd = 0.f;
        if (pad) {
          int s_g = s0 + ss * 16 + r;
          if (mask[(size_t)b * S + s_g]) padd = -INFINITY;
        }
#pragma unroll
        for (int reg = 0; reg < 4; ++reg) {
          float v = sc[ss][reg] + padd;
          if (diag) {
            int s_g = s0 + ss * 16 + r;
            int q_g = qg + g * 4 + reg;
            if (s_g > q_g) v = -INFINITY;
          }
          sv[ss][reg] = v;
          pmax[reg] = fmaxf(pmax[reg], v);
        }
      }

      float tm[4];
#pragma unroll
      for (int reg = 0; reg < 4; ++reg) tm[reg] = rowmax16(pmax[reg]);
      float dmax = fmaxf(fmaxf(tm[0] - mrun[u][0], tm[1] - mrun[u][1]),
                         fmaxf(tm[2] - mrun[u][2], tm[3] - mrun[u][3]));
      if (__any(dmax > DEFER_THR)) {
#pragma unroll
        for (int reg = 0; reg < 4; ++reg) {
          float newm = fmaxf(mrun[u][reg], tm[reg]);
          float alpha = (newm == -INFINITY) ? 1.f : exp2f(mrun[u][reg] - newm);
          mrun[u][reg] = newm;
          float rs = 0.f;
#pragma unroll
          for (int ss = 0; ss < 4; ++ss) {
            float p = (newm == -INFINITY) ? 0.f : exp2f(sv[ss][reg] - newm);
            sv[ss][reg] = p;
            rs += p;
          }
          rs = rowsum16(rs);
          lrun[u][reg] = lrun[u][reg] * alpha + rs;
#pragma unroll
          for (int df = 0; df < 4; ++df) acc[u][df][reg] *= alpha;
        }
      } else {
#pragma unroll
        for (int reg = 0; reg < 4; ++reg) {
          float m = mrun[u][reg];
          float rs = 0.f;
#pragma unroll
          for (int ss = 0; ss < 4; ++ss) {
            float p = (m == -INFINITY) ? 0.f : exp2f(sv[ss][reg] - m);
            sv[ss][reg] = p;
            rs += p;
          }
          rs = rowsum16(rs);
          lrun[u][reg] += rs;
        }
      }

#pragma unroll
      for (int ss = 0; ss < 4; ++ss) {
#pragma unroll
        for (int reg = 0; reg < 4; ++reg) {
          int qrow = g * 4 + reg;
          int byteoff = qrow * 128 + (ss * 16 + r) * 2;
          u32 bits = __builtin_bit_cast(u32, sv[ss][reg]);
          *(u16*)((char*)Pw + (byteoff ^ ((qrow & 7) << 4))) = (u16)(bits >> 16);
        }
      }

      __builtin_amdgcn_s_setprio(1);
#pragma unroll
      for (int sc2 = 0; sc2 < 2; ++sc2) {
        int pbyte = r * 128 + sc2 * 64 + g * 16;
        bf16x8 pf = *(const bf16x8*)((const char*)Pw + (pbyte ^ ((r & 7) << 4)));
#pragma unroll
        for (int df = 0; df < 4; ++df) {
          int vrow = df * 16 + r;
          int vbyte = vrow * 128 + sc2 * 64 + g * 16;
          bf16x8 vf = *(const bf16x8*)((const char*)Vb + (vbyte ^ ((vrow & 7) << 4)));
          acc[u][df] = __builtin_amdgcn_mfma_f32_16x16x32_bf16(pf, vf, acc[u][df], 0, 0, 0);
        }
      }
      __builtin_amdgcn_s_setprio(0);
    }
  }

#pragma unroll
  for (int u = 0; u < 2; ++u) {
#pragma unroll
    for (int reg = 0; reg < 4; ++reg) {
      float l = lrun[u][reg];
      float inv = (l > 0.f) ? 1.f / l : 0.f;
      int t = qw + u * 16 + g * 4 + reg;
#pragma unroll
      for (int df = 0; df < 4; ++df) {
        float vo = acc[u][df][reg] * inv;
        O[((size_t)b * 1024 + t) * 1024 + h * 64 + df * 16 + r] = f2bf(vo);
      }
    }
  }
}

// ---------- launch ----------

extern "C" void kernel_launch(void* const* d_in, const int* in_sizes, int n_in,
                              void* d_out, int out_size, void* d_ws, size_t ws_size,
                              hipStream_t stream) {
  const float* q  = (const float*)d_in[0];
  const float* k  = (const float*)d_in[1];
  const float* v  = (const float*)d_in[2];
  const unsigned char* mask = (const unsigned char*)d_in[3];
  const float* Wq = (const float*)d_in[4];
  const float* bq = (const float*)d_in[5];
  const float* Wk = (const float*)d_in[6];
  const float* bk = (const float*)d_in[7];
  const float* Wv = (const float*)d_in[8];
  const float* bv = (const float*)d_in[9];
  const float* Wo = (const float*)d_in[10];
  const float* bo = (const float*)d_in[11];

  const int M = 8192, N = 1024, K = 1024;
  const size_t MB = 1u << 20;
  char* ws = (char*)d_ws;

  u16* Aq   = (u16*)(ws);                 // 16MB, reused as AttO after QKV GEMM
  u16* Ak   = (u16*)(ws + 16 * MB);
  u16* Av   = (u16*)(ws + 32 * MB);
  u16* Qh   = (u16*)(ws + 48 * MB);
  u16* Kh   = (u16*)(ws + 64 * MB);
  u16* Vt   = (u16*)(ws + 80 * MB);
  u16* Wqb  = (u16*)(ws + 96 * MB);
  u16* Wkb  = Wqb + (1u << 20);
  u16* Wvb  = Wkb + (1u << 20);
  u16* Wob  = Wvb + (1u << 20);
  unsigned char* flags = (unsigned char*)(ws + 104 * MB);
  u16* AttO = Aq;

  cvt_all<<<dim3(1024, 7), 256, 0, stream>>>(
      (const float4*)q, (const float4*)k, (const float4*)v,
      (const float4*)Wq, (const float4*)Wk, (const float4*)Wv, (const float4*)Wo,
      (ushort4*)Aq, (ushort4*)Ak, (ushort4*)Av,
      (ushort4*)Wqb, (ushort4*)Wkb, (ushort4*)Wvb, (ushort4*)Wob,
      (M * K) / 4, (N * K) / 4);
  mask_flags<<<1, 128, 0, stream>>>(mask, flags);

  gemm_qkv8b<<<dim3(8, 32, 3), 512, 0, stream>>>(
      Aq, Ak, Av, Wqb, Wkb, Wvb, bq, bk, bv, Qh, Kh, Vt, M, N, K);

  attn_fwd<<<dim3(128, 8), 256, 0, stream>>>(Qh, Kh, Vt, mask, flags, AttO);

  gemm_o<<<dim3(8, 64), 256, 0, stream>>>(
      AttO, Wob, bo, (float*)d_out, M, N, K);
}